// Round 13
// baseline (329.543 us; speedup 1.0000x reference)
//
#include <hip/hip_runtime.h>
#include <math.h>

#define N_SAMP 4096
#define NS     7
#define DT_F   1e-5f
#define B0_F   80.0f
#define T2_F   1.0f
#define SW_F   1000.0f
#define TWO_PI 6.2831853071795864769f
#define NSWEEP_S 6

// ws layout (floats): Vt 0..16384 | lam 16384..16512 | U 16512..32896 |
//                     M 32896..49280 | W 49280..65664 | fidf(float2) 65664..73856 |
//                     part 73856..139392
// out (f32, 24576): ReFID [0,4096) | time [4096,8192) |
//                   Re shifted spec [8192,16384) | freq [16384,24576)

// Sector eigensolver: H0 block-diagonal in popcount sectors, sizes C(7,s).
// One workgroup per sector; one WAVE per rotation pair (lockstep removes the
// (c,s) staging phase): 2 barriers/round.
__global__ __launch_bounds__(1024) void k_eig(const float* __restrict__ h,
                                              float* __restrict__ Vt_full,
                                              float* __restrict__ lam_out) {
    const int nsz_[8]   = {1, 7, 21, 35, 35, 21, 7, 1};
    const int nbase_[8] = {0, 1, 8, 29, 64, 99, 120, 127};
    const int s    = blockIdx.x;
    const int ns   = nsz_[s];
    const int base = nbase_[s];
    const int tid  = threadIdx.x;
    const int wave = tid >> 6;
    const int lane = tid & 63;

    __shared__ float As[36 * 37];
    __shared__ float Vs[36 * 37];
    __shared__ int   st[36];
    __shared__ float hs[49];
    __shared__ float cc[18], ss[18];

    if (tid < 49) hs[tid] = h[tid];
    if (tid == 0) {
        int cnt = 0;
        for (int r = 0; r < 128; ++r) if (__popc(r) == s) st[cnt++] = r;
    }
    for (int t = tid; t < 36 * 37; t += 1024) { As[t] = 0.f; Vs[t] = 0.f; }
    __syncthreads();

    // Build sector Hamiltonian from h
    for (int t = tid; t < ns * ns; t += 1024) {
        int i = t / ns, j = t % ns;
        int r = st[i], c = st[j];
        float val = 0.f;
        if (r == c) {
            float acc = 0.f;
            for (int a = 0; a < 7; ++a) {
                float za = ((r >> (6 - a)) & 1) ? -0.5f : 0.5f;
                acc += B0_F * hs[a * 7 + a] * za;
                for (int b = a + 1; b < 7; ++b) {
                    float zb = ((r >> (6 - b)) & 1) ? -0.5f : 0.5f;
                    acc += hs[a * 7 + b] * za * zb;
                }
            }
            val = TWO_PI * acc;
        } else {
            int x = r ^ c;
            if (__popc(x) == 2) {
                int u = 31 - __clz(x);
                int v = __ffs(x) - 1;
                if (((r >> u) & 1) != ((r >> v) & 1))
                    val = TWO_PI * 0.5f * hs[(6 - u) * 7 + (6 - v)];
            }
        }
        As[i * 37 + j] = val;
    }
    for (int i = tid; i < ns; i += 1024) Vs[i * 37 + i] = 1.f;
    __syncthreads();

    if (ns > 1) {
        const int m      = ns + 1;          // sector sizes odd -> m even
        const int nr     = m - 1;
        const int npairs = m / 2;
        for (int sweep = 0; sweep < NSWEEP_S; ++sweep) {
            for (int t = 0; t < nr; ++t) {
                // ---- phase R: row rotations of A and V (+ (c,s) computed in-wave)
#pragma unroll 2
                for (int rep = 0; rep < 2; ++rep) {
                    int jj = wave + rep * 16;
                    if (jj < npairs) {
                        int p, q;
                        if (jj == 0) { p = t; q = m - 1; }
                        else {
                            int a1 = (t + jj) % nr;
                            int b1 = (t + nr - jj) % nr;
                            p = a1 < b1 ? a1 : b1;
                            q = a1 < b1 ? b1 : a1;
                        }
                        if (q < ns) {   // q==ns is the padded element -> no-op
                            float app = As[p * 37 + p];
                            float aqq = As[q * 37 + q];
                            float apq = As[p * 37 + q];
                            float c = 1.f, sn = 0.f;
                            if (fabsf(apq) >= 1e-30f) {
                                float tau = (aqq - app) / (2.f * apq);
                                float tt  = copysignf(1.f / (fabsf(tau) + sqrtf(1.f + tau * tau)), tau);
                                c  = rsqrtf(1.f + tt * tt);
                                sn = tt * c;
                            }
                            if (lane == 0) { cc[jj] = c; ss[jj] = sn; }
                            if (lane < ns) {
                                float ap = As[p * 37 + lane], aq = As[q * 37 + lane];
                                As[p * 37 + lane] = c * ap - sn * aq;
                                As[q * 37 + lane] = sn * ap + c * aq;
                                float vp = Vs[p * 37 + lane], vq = Vs[q * 37 + lane];
                                Vs[p * 37 + lane] = c * vp - sn * vq;
                                Vs[q * 37 + lane] = sn * vp + c * vq;
                            }
                        }
                    }
                }
                __syncthreads();
                // ---- phase C: column rotations of A
#pragma unroll 2
                for (int rep = 0; rep < 2; ++rep) {
                    int jj = wave + rep * 16;
                    if (jj < npairs) {
                        int p, q;
                        if (jj == 0) { p = t; q = m - 1; }
                        else {
                            int a1 = (t + jj) % nr;
                            int b1 = (t + nr - jj) % nr;
                            p = a1 < b1 ? a1 : b1;
                            q = a1 < b1 ? b1 : a1;
                        }
                        if (q < ns && lane < ns) {
                            float c = cc[jj], sn = ss[jj];
                            float ap = As[lane * 37 + p], aq = As[lane * 37 + q];
                            As[lane * 37 + p] = c * ap - sn * aq;
                            As[lane * 37 + q] = sn * ap + c * aq;
                        }
                    }
                }
                __syncthreads();
            }
        }
    }

    for (int i = tid; i < ns; i += 1024) lam_out[base + i] = As[i * 37 + i];
    for (int t = tid; t < ns * 128; t += 1024)
        Vt_full[(base + t / 128) * 128 + (t & 127)] = 0.f;
    __syncthreads();
    for (int t = tid; t < ns * ns; t += 1024) {
        int i = t / ns, j = t % ns;
        Vt_full[(base + i) * 128 + st[j]] = Vs[i * 37 + j];
    }
}

__global__ void k_opv(const float* __restrict__ Vt, float* __restrict__ U) {
    int idx = blockIdx.x * 256 + threadIdx.x;
    int b = idx >> 7, r = idx & 127;
    float acc = 0.f;
#pragma unroll
    for (int p = 0; p < 7; ++p)
        if (!((r >> p) & 1)) acc += Vt[b * 128 + r + (1 << p)];
    U[b * 128 + r] = acc;
}

__global__ void k_m(const float* __restrict__ Vt, const float* __restrict__ U,
                    float* __restrict__ M) {
    __shared__ float va[128];
    int a = blockIdx.x, b = threadIdx.x;
    va[b] = Vt[a * 128 + b];
    __syncthreads();
    float acc = 0.f;
    for (int r = 0; r < 128; ++r) acc += va[r] * U[b * 128 + r];
    M[a * 128 + b] = acc;
}

__global__ void k_w(const float* __restrict__ M, float* __restrict__ W) {
    int idx = blockIdx.x * 256 + threadIdx.x;
    int a = idx >> 7, b = idx & 127;
    W[idx] = M[idx] * 0.5f * (M[idx] + M[b * 128 + a]);
}

// 8 samples per block via phasor recurrence
__global__ __launch_bounds__(256) void k_fid(const float* __restrict__ W,
                                             const float* __restrict__ lam,
                                             float* __restrict__ fidfF,
                                             float* __restrict__ out) {
    __shared__ float2 cb0[128], dd[128];
    __shared__ float  lred[4][16];
    const int n0  = blockIdx.x * 8;
    const int tid = threadIdx.x;
    const float t0 = (float)n0 * DT_F;
    if (tid < 128) {
        float sn, cs;
        sincosf(lam[tid] * t0, &sn, &cs);
        cb0[tid] = make_float2(cs, -sn);
        sincosf(lam[tid] * DT_F, &sn, &cs);
        dd[tid] = make_float2(cs, -sn);
    }
    __syncthreads();

    float ar0=0,ar1=0,ar2=0,ar3=0,ar4=0,ar5=0,ar6=0,ar7=0;
    float ai0=0,ai1=0,ai2=0,ai3=0,ai4=0,ai5=0,ai6=0,ai7=0;
    for (int i = 0; i < 64; ++i) {
        int m = i * 256 + tid;
        int a = m >> 7, b = m & 127;
        float w = W[m];
        float2 ca = cb0[a], cbv = cb0[b];
        float2 da = dd[a],  db  = dd[b];
        float zr = ca.x * cbv.x + ca.y * cbv.y;
        float zi = ca.x * cbv.y - ca.y * cbv.x;
        float fr = da.x * db.x + da.y * db.y;
        float fi = da.x * db.y - da.y * db.x;
        ar0 += w * zr; ai0 += w * zi; { float tr = zr*fr - zi*fi; zi = zr*fi + zi*fr; zr = tr; }
        ar1 += w * zr; ai1 += w * zi; { float tr = zr*fr - zi*fi; zi = zr*fi + zi*fr; zr = tr; }
        ar2 += w * zr; ai2 += w * zi; { float tr = zr*fr - zi*fi; zi = zr*fi + zi*fr; zr = tr; }
        ar3 += w * zr; ai3 += w * zi; { float tr = zr*fr - zi*fi; zi = zr*fi + zi*fr; zr = tr; }
        ar4 += w * zr; ai4 += w * zi; { float tr = zr*fr - zi*fi; zi = zr*fi + zi*fr; zr = tr; }
        ar5 += w * zr; ai5 += w * zi; { float tr = zr*fr - zi*fi; zi = zr*fi + zi*fr; zr = tr; }
        ar6 += w * zr; ai6 += w * zi; { float tr = zr*fr - zi*fi; zi = zr*fi + zi*fr; zr = tr; }
        ar7 += w * zr; ai7 += w * zi;
    }

    const int wave = tid >> 6, lane = tid & 63;
    float acc[16] = {ar0,ai0,ar1,ai1,ar2,ai2,ar3,ai3,ar4,ai4,ar5,ai5,ar6,ai6,ar7,ai7};
#pragma unroll 16
    for (int v = 0; v < 16; ++v) {
        float x = acc[v];
        for (int off = 32; off > 0; off >>= 1) x += __shfl_down(x, off);
        if (lane == 0) lred[wave][v] = x;
    }
    __syncthreads();
    if (tid < 16) {
        float x = lred[0][tid] + lred[1][tid] + lred[2][tid] + lred[3][tid];
        int jj = tid >> 1, c = tid & 1;
        int n = n0 + jj;
        float ap = expf(-(DT_F / T2_F) * (float)n);
        x *= ap;
        fidfF[2 * n + c] = x;
        if (c == 0) out[n] = x;
    }
}

// split-K shifted-spectrum partials: 8 chunks x 32 k-groups
__global__ __launch_bounds__(256) void k_dft(const float2* __restrict__ fidf,
                                             float* __restrict__ part) {
    __shared__ float2 fs[512];
    const int tid = threadIdx.x;
    const int ch  = blockIdx.x >> 5;
    const int kb  = blockIdx.x & 31;
    const int n0  = ch * 512;
    fs[tid]       = fidf[n0 + tid];
    fs[tid + 256] = fidf[n0 + tid + 256];
    __syncthreads();
    const int k = kb * 256 + tid;
    const int K = (k + 4096) & 8191;
    const float C = TWO_PI / 8192.0f;
    int idx = (n0 * K) & 8191;
    float ar = 0.f;
    for (int i = 0; i < 512; ++i) {
        float2 s = fs[i];
        float sn, cs;
        __sincosf(C * (float)idx, &sn, &cs);
        ar += s.x * cs + s.y * sn;
        idx = (idx + K) & 8191;
    }
    part[ch * 8192 + k] = ar;
}

// reduce partials + write axes
__global__ void k_dredax(const float* __restrict__ part, float* __restrict__ out) {
    int i = blockIdx.x * 256 + threadIdx.x;   // 0..8191
    float s = 0.f;
#pragma unroll
    for (int ch = 0; ch < 8; ++ch) s += part[ch * 8192 + i];
    out[8192 + i] = s;
    out[16384 + i] = -0.5f * SW_F + (float)i * (SW_F / (float)(2 * N_SAMP - 1));
    if (i < N_SAMP)
        out[4096 + i] = (float)i * ((N_SAMP / SW_F) / (float)(N_SAMP - 1));
}

extern "C" void kernel_launch(void* const* d_in, const int* in_sizes, int n_in,
                              void* d_out, int out_size, void* d_ws, size_t ws_size,
                              hipStream_t stream) {
    const float* h = (const float*)d_in[0];
    float* out = (float*)d_out;
    float* ws  = (float*)d_ws;

    float*  Vt   = ws;
    float*  lam  = ws + 16384;
    float*  U    = ws + 16512;
    float*  M    = ws + 32896;
    float*  W    = ws + 49280;
    float*  fidfF= ws + 65664;
    float2* fidf = (float2*)(ws + 65664);
    float*  part = ws + 73856;

    k_eig<<<8, 1024, 0, stream>>>(h, Vt, lam);
    k_opv<<<64, 256, 0, stream>>>(Vt, U);
    k_m<<<128, 128, 0, stream>>>(Vt, U, M);
    k_w<<<64, 256, 0, stream>>>(M, W);
    k_fid<<<512, 256, 0, stream>>>(W, lam, fidfF, out);
    k_dft<<<256, 256, 0, stream>>>(fidf, part);
    k_dredax<<<32, 256, 0, stream>>>(part, out);
}

// Round 14
// 193.740 us; speedup vs baseline: 1.7010x; 1.7010x over previous
//
#include <hip/hip_runtime.h>
#include <math.h>

#define N_SAMP 4096
#define NS     7
#define DT_F   1e-5f
#define B0_F   80.0f
#define T2_F   1.0f
#define SW_F   1000.0f
#define TWO_PI 6.2831853071795864769f
#define NSWEEP_S 4

// ws layout (floats): Vt 0..16384 | lam 16384..16512 | U 16512..32896 |
//                     M 32896..49280 | W 49280..65664 | fidf(float2) 65664..73856 |
//                     part 73856..139392
// out (f32, 24576): ReFID [0,4096) | time [4096,8192) |
//                   Re shifted spec [8192,16384) | freq [16384,24576)

// Sector eigensolver: H0 block-diagonal in popcount sectors, sizes C(7,s).
// One workgroup/sector; wave-per-pair; precomputed tournament table;
// (c,s) in-register across the 2 barriers/round.
__global__ __launch_bounds__(1024) void k_eig(const float* __restrict__ h,
                                              float* __restrict__ Vt_full,
                                              float* __restrict__ lam_out) {
    const int nsz_[8]   = {1, 7, 21, 35, 35, 21, 7, 1};
    const int nbase_[8] = {0, 1, 8, 29, 64, 99, 120, 127};
    const int s    = blockIdx.x;
    const int ns   = nsz_[s];
    const int base = nbase_[s];
    const int tid  = threadIdx.x;
    const int wave = tid >> 6;
    const int lane = tid & 63;

    __shared__ float As[36 * 37];
    __shared__ float Vs[36 * 37];
    __shared__ int   st[36];
    __shared__ float hs[49];
    __shared__ int   ppt[35 * 18];    // tournament table: (p<<8)|q per (round t, pair j)

    const int m      = ns + 1;        // sector sizes odd -> m even
    const int nr     = m - 1;
    const int npairs = m / 2;

    if (tid < 49) hs[tid] = h[tid];
    if (tid == 0) {
        int cnt = 0;
        for (int r = 0; r < 128; ++r) if (__popc(r) == s) st[cnt++] = r;
    }
    // tournament table (modulo done once)
    if (ns > 1) {
        for (int e = tid; e < nr * npairs; e += 1024) {
            int t = e / npairs, j = e - (e / npairs) * npairs;
            int p, q;
            if (j == 0) { p = t; q = m - 1; }
            else {
                int a1 = (t + j) % nr;
                int b1 = (t + nr - j) % nr;
                p = a1 < b1 ? a1 : b1;
                q = a1 < b1 ? b1 : a1;
            }
            ppt[t * npairs + j] = (p << 8) | q;
        }
    }
    for (int t = tid; t < 36 * 37; t += 1024) { As[t] = 0.f; Vs[t] = 0.f; }
    __syncthreads();

    // Build sector Hamiltonian from h
    for (int t = tid; t < ns * ns; t += 1024) {
        int i = t / ns, j = t % ns;
        int r = st[i], c = st[j];
        float val = 0.f;
        if (r == c) {
            float acc = 0.f;
            for (int a = 0; a < 7; ++a) {
                float za = ((r >> (6 - a)) & 1) ? -0.5f : 0.5f;
                acc += B0_F * hs[a * 7 + a] * za;
                for (int b = a + 1; b < 7; ++b) {
                    float zb = ((r >> (6 - b)) & 1) ? -0.5f : 0.5f;
                    acc += hs[a * 7 + b] * za * zb;
                }
            }
            val = TWO_PI * acc;
        } else {
            int x = r ^ c;
            if (__popc(x) == 2) {
                int u = 31 - __clz(x);
                int v = __ffs(x) - 1;
                if (((r >> u) & 1) != ((r >> v) & 1))
                    val = TWO_PI * 0.5f * hs[(6 - u) * 7 + (6 - v)];
            }
        }
        As[i * 37 + j] = val;
    }
    for (int i = tid; i < ns; i += 1024) Vs[i * 37 + i] = 1.f;
    __syncthreads();

    if (ns > 1) {
        for (int sweep = 0; sweep < NSWEEP_S; ++sweep) {
            for (int t = 0; t < nr; ++t) {
                const int* prow = &ppt[t * npairs];
                // (c,s) per rep kept in registers across the barrier
                float c0 = 1.f, s0 = 0.f, c1 = 1.f, s1 = 0.f;
                int   pq0 = -1, pq1 = -1;

                // ---- phase R: A-rows + V-rows; (c,s) from own pair's rows (safe in-wave)
#pragma unroll 2
                for (int rep = 0; rep < 2; ++rep) {
                    int jj = wave + rep * 16;
                    if (jj < npairs) {
                        int pq = prow[jj];
                        int p = pq >> 8, q = pq & 255;
                        if (q < ns) {
                            float app = As[p * 37 + p];
                            float aqq = As[q * 37 + q];
                            float apq = As[p * 37 + q];
                            float c = 1.f, sn = 0.f;
                            if (fabsf(apq) >= 1e-30f) {
                                float tau = (aqq - app) / (2.f * apq);
                                float tt  = copysignf(1.f / (fabsf(tau) + sqrtf(1.f + tau * tau)), tau);
                                c  = rsqrtf(1.f + tt * tt);
                                sn = tt * c;
                            }
                            if (rep == 0) { c0 = c; s0 = sn; pq0 = pq; }
                            else          { c1 = c; s1 = sn; pq1 = pq; }
                            if (lane < ns) {
                                float ap = As[p * 37 + lane], aq = As[q * 37 + lane];
                                As[p * 37 + lane] = c * ap - sn * aq;
                                As[q * 37 + lane] = sn * ap + c * aq;
                                float vp = Vs[p * 37 + lane], vq = Vs[q * 37 + lane];
                                Vs[p * 37 + lane] = c * vp - sn * vq;
                                Vs[q * 37 + lane] = sn * vp + c * vq;
                            }
                        }
                    }
                }
                __syncthreads();
                // ---- phase C: A-cols (uses registered (c,s))
                if (pq0 >= 0) {
                    int p = pq0 >> 8, q = pq0 & 255;
                    if (q < ns && lane < ns) {
                        float ap = As[lane * 37 + p], aq = As[lane * 37 + q];
                        As[lane * 37 + p] = c0 * ap - s0 * aq;
                        As[lane * 37 + q] = s0 * ap + c0 * aq;
                    }
                }
                if (pq1 >= 0) {
                    int p = pq1 >> 8, q = pq1 & 255;
                    if (q < ns && lane < ns) {
                        float ap = As[lane * 37 + p], aq = As[lane * 37 + q];
                        As[lane * 37 + p] = c1 * ap - s1 * aq;
                        As[lane * 37 + q] = s1 * ap + c1 * aq;
                    }
                }
                __syncthreads();
            }
        }
    }

    for (int i = tid; i < ns; i += 1024) lam_out[base + i] = As[i * 37 + i];
    for (int t = tid; t < ns * 128; t += 1024)
        Vt_full[(base + t / 128) * 128 + (t & 127)] = 0.f;
    __syncthreads();
    for (int t = tid; t < ns * ns; t += 1024) {
        int i = t / ns, j = t % ns;
        Vt_full[(base + i) * 128 + st[j]] = Vs[i * 37 + j];
    }
}

__global__ void k_opv(const float* __restrict__ Vt, float* __restrict__ U) {
    int idx = blockIdx.x * 256 + threadIdx.x;
    int b = idx >> 7, r = idx & 127;
    float acc = 0.f;
#pragma unroll
    for (int p = 0; p < 7; ++p)
        if (!((r >> p) & 1)) acc += Vt[b * 128 + r + (1 << p)];
    U[b * 128 + r] = acc;
}

__global__ void k_m(const float* __restrict__ Vt, const float* __restrict__ U,
                    float* __restrict__ M) {
    __shared__ float va[128];
    int a = blockIdx.x, b = threadIdx.x;
    va[b] = Vt[a * 128 + b];
    __syncthreads();
    float acc = 0.f;
    for (int r = 0; r < 128; ++r) acc += va[r] * U[b * 128 + r];
    M[a * 128 + b] = acc;
}

__global__ void k_w(const float* __restrict__ M, float* __restrict__ W) {
    int idx = blockIdx.x * 256 + threadIdx.x;
    int a = idx >> 7, b = idx & 127;
    W[idx] = M[idx] * 0.5f * (M[idx] + M[b * 128 + a]);
}

// 8 samples per block via phasor recurrence
__global__ __launch_bounds__(256) void k_fid(const float* __restrict__ W,
                                             const float* __restrict__ lam,
                                             float* __restrict__ fidfF,
                                             float* __restrict__ out) {
    __shared__ float2 cb0[128], dd[128];
    __shared__ float  lred[4][16];
    const int n0  = blockIdx.x * 8;
    const int tid = threadIdx.x;
    const float t0 = (float)n0 * DT_F;
    if (tid < 128) {
        float sn, cs;
        sincosf(lam[tid] * t0, &sn, &cs);
        cb0[tid] = make_float2(cs, -sn);
        sincosf(lam[tid] * DT_F, &sn, &cs);
        dd[tid] = make_float2(cs, -sn);
    }
    __syncthreads();

    float ar0=0,ar1=0,ar2=0,ar3=0,ar4=0,ar5=0,ar6=0,ar7=0;
    float ai0=0,ai1=0,ai2=0,ai3=0,ai4=0,ai5=0,ai6=0,ai7=0;
    for (int i = 0; i < 64; ++i) {
        int m = i * 256 + tid;
        int a = m >> 7, b = m & 127;
        float w = W[m];
        float2 ca = cb0[a], cbv = cb0[b];
        float2 da = dd[a],  db  = dd[b];
        float zr = ca.x * cbv.x + ca.y * cbv.y;
        float zi = ca.x * cbv.y - ca.y * cbv.x;
        float fr = da.x * db.x + da.y * db.y;
        float fi = da.x * db.y - da.y * db.x;
        ar0 += w * zr; ai0 += w * zi; { float tr = zr*fr - zi*fi; zi = zr*fi + zi*fr; zr = tr; }
        ar1 += w * zr; ai1 += w * zi; { float tr = zr*fr - zi*fi; zi = zr*fi + zi*fr; zr = tr; }
        ar2 += w * zr; ai2 += w * zi; { float tr = zr*fr - zi*fi; zi = zr*fi + zi*fr; zr = tr; }
        ar3 += w * zr; ai3 += w * zi; { float tr = zr*fr - zi*fi; zi = zr*fi + zi*fr; zr = tr; }
        ar4 += w * zr; ai4 += w * zi; { float tr = zr*fr - zi*fi; zi = zr*fi + zi*fr; zr = tr; }
        ar5 += w * zr; ai5 += w * zi; { float tr = zr*fr - zi*fi; zi = zr*fi + zi*fr; zr = tr; }
        ar6 += w * zr; ai6 += w * zi; { float tr = zr*fr - zi*fi; zi = zr*fi + zi*fr; zr = tr; }
        ar7 += w * zr; ai7 += w * zi;
    }

    const int wave = tid >> 6, lane = tid & 63;
    float acc[16] = {ar0,ai0,ar1,ai1,ar2,ai2,ar3,ai3,ar4,ai4,ar5,ai5,ar6,ai6,ar7,ai7};
#pragma unroll 16
    for (int v = 0; v < 16; ++v) {
        float x = acc[v];
        for (int off = 32; off > 0; off >>= 1) x += __shfl_down(x, off);
        if (lane == 0) lred[wave][v] = x;
    }
    __syncthreads();
    if (tid < 16) {
        float x = lred[0][tid] + lred[1][tid] + lred[2][tid] + lred[3][tid];
        int jj = tid >> 1, c = tid & 1;
        int n = n0 + jj;
        float ap = expf(-(DT_F / T2_F) * (float)n);
        x *= ap;
        fidfF[2 * n + c] = x;
        if (c == 0) out[n] = x;
    }
}

// split-K shifted-spectrum partials: 8 chunks x 32 k-groups
__global__ __launch_bounds__(256) void k_dft(const float2* __restrict__ fidf,
                                             float* __restrict__ part) {
    __shared__ float2 fs[512];
    const int tid = threadIdx.x;
    const int ch  = blockIdx.x >> 5;
    const int kb  = blockIdx.x & 31;
    const int n0  = ch * 512;
    fs[tid]       = fidf[n0 + tid];
    fs[tid + 256] = fidf[n0 + tid + 256];
    __syncthreads();
    const int k = kb * 256 + tid;
    const int K = (k + 4096) & 8191;
    const float C = TWO_PI / 8192.0f;
    int idx = (n0 * K) & 8191;
    float ar = 0.f;
    for (int i = 0; i < 512; ++i) {
        float2 s = fs[i];
        float sn, cs;
        __sincosf(C * (float)idx, &sn, &cs);
        ar += s.x * cs + s.y * sn;
        idx = (idx + K) & 8191;
    }
    part[ch * 8192 + k] = ar;
}

// reduce partials + write axes
__global__ void k_dredax(const float* __restrict__ part, float* __restrict__ out) {
    int i = blockIdx.x * 256 + threadIdx.x;   // 0..8191
    float s = 0.f;
#pragma unroll
    for (int ch = 0; ch < 8; ++ch) s += part[ch * 8192 + i];
    out[8192 + i] = s;
    out[16384 + i] = -0.5f * SW_F + (float)i * (SW_F / (float)(2 * N_SAMP - 1));
    if (i < N_SAMP)
        out[4096 + i] = (float)i * ((N_SAMP / SW_F) / (float)(N_SAMP - 1));
}

extern "C" void kernel_launch(void* const* d_in, const int* in_sizes, int n_in,
                              void* d_out, int out_size, void* d_ws, size_t ws_size,
                              hipStream_t stream) {
    const float* h = (const float*)d_in[0];
    float* out = (float*)d_out;
    float* ws  = (float*)d_ws;

    float*  Vt   = ws;
    float*  lam  = ws + 16384;
    float*  U    = ws + 16512;
    float*  M    = ws + 32896;
    float*  W    = ws + 49280;
    float*  fidfF= ws + 65664;
    float2* fidf = (float2*)(ws + 65664);
    float*  part = ws + 73856;

    k_eig<<<8, 1024, 0, stream>>>(h, Vt, lam);
    k_opv<<<64, 256, 0, stream>>>(Vt, U);
    k_m<<<128, 128, 0, stream>>>(Vt, U, M);
    k_w<<<64, 256, 0, stream>>>(M, W);
    k_fid<<<512, 256, 0, stream>>>(W, lam, fidfF, out);
    k_dft<<<256, 256, 0, stream>>>(fidf, part);
    k_dredax<<<32, 256, 0, stream>>>(part, out);
}

// Round 15
// 180.060 us; speedup vs baseline: 1.8302x; 1.0760x over previous
//
#include <hip/hip_runtime.h>
#include <math.h>

#define N_SAMP 4096
#define NS     7
#define DT_F   1e-5f
#define B0_F   80.0f
#define T2_F   1.0f
#define SW_F   1000.0f
#define TWO_PI 6.2831853071795864769f
#define NSWEEP_S 3
#define EIG_T  576   // 9 waves; jj = wave + rep*9 covers 18 pairs with no idle reps

// ws layout (floats): Vt 0..16384 | lam 16384..16512 | U 16512..32896 |
//                     M 32896..49280 | W 49280..65664 | fidf(float2) 65664..73856 |
//                     part 73856..139392
// out (f32, 24576): ReFID [0,4096) | time [4096,8192) |
//                   Re shifted spec [8192,16384) | freq [16384,24576)

__global__ __launch_bounds__(EIG_T) void k_eig(const float* __restrict__ h,
                                               float* __restrict__ Vt_full,
                                               float* __restrict__ lam_out) {
    const int nsz_[8]   = {1, 7, 21, 35, 35, 21, 7, 1};
    const int nbase_[8] = {0, 1, 8, 29, 64, 99, 120, 127};
    const int s    = blockIdx.x;
    const int ns   = nsz_[s];
    const int base = nbase_[s];
    const int tid  = threadIdx.x;
    const int wave = tid >> 6;
    const int lane = tid & 63;

    __shared__ float As[36 * 37];
    __shared__ float Vs[36 * 37];
    __shared__ int   st[36];
    __shared__ float hs[49];
    __shared__ int   ppt[35 * 18];    // tournament table: (p<<8)|q per (round, pair)

    const int m      = ns + 1;        // sector sizes odd -> m even
    const int nr     = m - 1;
    const int npairs = m / 2;

    if (tid < 49) hs[tid] = h[tid];
    if (tid == 0) {
        int cnt = 0;
        for (int r = 0; r < 128; ++r) if (__popc(r) == s) st[cnt++] = r;
    }
    if (ns > 1) {
        for (int e = tid; e < nr * npairs; e += EIG_T) {
            int t = e / npairs, j = e - t * npairs;
            int p, q;
            if (j == 0) { p = t; q = m - 1; }
            else {
                int a1 = (t + j) % nr;
                int b1 = (t + nr - j) % nr;
                p = a1 < b1 ? a1 : b1;
                q = a1 < b1 ? b1 : a1;
            }
            ppt[t * npairs + j] = (p << 8) | q;
        }
    }
    for (int t = tid; t < 36 * 37; t += EIG_T) { As[t] = 0.f; Vs[t] = 0.f; }
    __syncthreads();

    // Build sector Hamiltonian from h
    for (int t = tid; t < ns * ns; t += EIG_T) {
        int i = t / ns, j = t % ns;
        int r = st[i], c = st[j];
        float val = 0.f;
        if (r == c) {
            float acc = 0.f;
            for (int a = 0; a < 7; ++a) {
                float za = ((r >> (6 - a)) & 1) ? -0.5f : 0.5f;
                acc += B0_F * hs[a * 7 + a] * za;
                for (int b = a + 1; b < 7; ++b) {
                    float zb = ((r >> (6 - b)) & 1) ? -0.5f : 0.5f;
                    acc += hs[a * 7 + b] * za * zb;
                }
            }
            val = TWO_PI * acc;
        } else {
            int x = r ^ c;
            if (__popc(x) == 2) {
                int u = 31 - __clz(x);
                int v = __ffs(x) - 1;
                if (((r >> u) & 1) != ((r >> v) & 1))
                    val = TWO_PI * 0.5f * hs[(6 - u) * 7 + (6 - v)];
            }
        }
        As[i * 37 + j] = val;
    }
    for (int i = tid; i < ns; i += EIG_T) Vs[i * 37 + i] = 1.f;
    __syncthreads();

    if (ns > 1) {
        for (int sweep = 0; sweep < NSWEEP_S; ++sweep) {
            for (int t = 0; t < nr; ++t) {
                const int* prow = &ppt[t * npairs];
                float c0 = 1.f, s0 = 0.f, c1 = 1.f, s1 = 0.f;
                int   pq0 = -1, pq1 = -1;

                // ---- phase R: A-rows + V-rows; (c,s) computed in-wave, kept in regs
#pragma unroll 2
                for (int rep = 0; rep < 2; ++rep) {
                    int jj = wave + rep * 9;
                    if (jj < npairs) {
                        int pq = prow[jj];
                        int p = pq >> 8, q = pq & 255;
                        if (q < ns) {
                            float app = As[p * 37 + p];
                            float aqq = As[q * 37 + q];
                            float apq = As[p * 37 + q];
                            float c = 1.f, sn = 0.f;
                            if (fabsf(apq) >= 1e-30f) {
                                float tau = (aqq - app) / (2.f * apq);
                                float tt  = copysignf(1.f / (fabsf(tau) + sqrtf(1.f + tau * tau)), tau);
                                c  = rsqrtf(1.f + tt * tt);
                                sn = tt * c;
                            }
                            if (rep == 0) { c0 = c; s0 = sn; pq0 = pq; }
                            else          { c1 = c; s1 = sn; pq1 = pq; }
                            if (lane < ns) {
                                float ap = As[p * 37 + lane], aq = As[q * 37 + lane];
                                As[p * 37 + lane] = c * ap - sn * aq;
                                As[q * 37 + lane] = sn * ap + c * aq;
                                float vp = Vs[p * 37 + lane], vq = Vs[q * 37 + lane];
                                Vs[p * 37 + lane] = c * vp - sn * vq;
                                Vs[q * 37 + lane] = sn * vp + c * vq;
                            }
                        }
                    }
                }
                __syncthreads();
                // ---- phase C: A-cols (registered (c,s))
                if (pq0 >= 0) {
                    int p = pq0 >> 8, q = pq0 & 255;
                    if (q < ns && lane < ns) {
                        float ap = As[lane * 37 + p], aq = As[lane * 37 + q];
                        As[lane * 37 + p] = c0 * ap - s0 * aq;
                        As[lane * 37 + q] = s0 * ap + c0 * aq;
                    }
                }
                if (pq1 >= 0) {
                    int p = pq1 >> 8, q = pq1 & 255;
                    if (q < ns && lane < ns) {
                        float ap = As[lane * 37 + p], aq = As[lane * 37 + q];
                        As[lane * 37 + p] = c1 * ap - s1 * aq;
                        As[lane * 37 + q] = s1 * ap + c1 * aq;
                    }
                }
                __syncthreads();
            }
        }
    }

    for (int i = tid; i < ns; i += EIG_T) lam_out[base + i] = As[i * 37 + i];
    for (int t = tid; t < ns * 128; t += EIG_T)
        Vt_full[(base + t / 128) * 128 + (t & 127)] = 0.f;
    __syncthreads();
    for (int t = tid; t < ns * ns; t += EIG_T) {
        int i = t / ns, j = t % ns;
        Vt_full[(base + i) * 128 + st[j]] = Vs[i * 37 + j];
    }
}

__global__ void k_opv(const float* __restrict__ Vt, float* __restrict__ U) {
    int idx = blockIdx.x * 256 + threadIdx.x;
    int b = idx >> 7, r = idx & 127;
    float acc = 0.f;
#pragma unroll
    for (int p = 0; p < 7; ++p)
        if (!((r >> p) & 1)) acc += Vt[b * 128 + r + (1 << p)];
    U[b * 128 + r] = acc;
}

__global__ void k_m(const float* __restrict__ Vt, const float* __restrict__ U,
                    float* __restrict__ M) {
    __shared__ float va[128];
    int a = blockIdx.x, b = threadIdx.x;
    va[b] = Vt[a * 128 + b];
    __syncthreads();
    float acc = 0.f;
    for (int r = 0; r < 128; ++r) acc += va[r] * U[b * 128 + r];
    M[a * 128 + b] = acc;
}

__global__ void k_w(const float* __restrict__ M, float* __restrict__ W) {
    int idx = blockIdx.x * 256 + threadIdx.x;
    int a = idx >> 7, b = idx & 127;
    W[idx] = M[idx] * 0.5f * (M[idx] + M[b * 128 + a]);
}

// 8 samples per block via phasor recurrence
__global__ __launch_bounds__(256) void k_fid(const float* __restrict__ W,
                                             const float* __restrict__ lam,
                                             float* __restrict__ fidfF,
                                             float* __restrict__ out) {
    __shared__ float2 cb0[128], dd[128];
    __shared__ float  lred[4][16];
    const int n0  = blockIdx.x * 8;
    const int tid = threadIdx.x;
    const float t0 = (float)n0 * DT_F;
    if (tid < 128) {
        float sn, cs;
        sincosf(lam[tid] * t0, &sn, &cs);
        cb0[tid] = make_float2(cs, -sn);
        sincosf(lam[tid] * DT_F, &sn, &cs);
        dd[tid] = make_float2(cs, -sn);
    }
    __syncthreads();

    float ar0=0,ar1=0,ar2=0,ar3=0,ar4=0,ar5=0,ar6=0,ar7=0;
    float ai0=0,ai1=0,ai2=0,ai3=0,ai4=0,ai5=0,ai6=0,ai7=0;
    for (int i = 0; i < 64; ++i) {
        int m = i * 256 + tid;
        int a = m >> 7, b = m & 127;
        float w = W[m];
        float2 ca = cb0[a], cbv = cb0[b];
        float2 da = dd[a],  db  = dd[b];
        float zr = ca.x * cbv.x + ca.y * cbv.y;
        float zi = ca.x * cbv.y - ca.y * cbv.x;
        float fr = da.x * db.x + da.y * db.y;
        float fi = da.x * db.y - da.y * db.x;
        ar0 += w * zr; ai0 += w * zi; { float tr = zr*fr - zi*fi; zi = zr*fi + zi*fr; zr = tr; }
        ar1 += w * zr; ai1 += w * zi; { float tr = zr*fr - zi*fi; zi = zr*fi + zi*fr; zr = tr; }
        ar2 += w * zr; ai2 += w * zi; { float tr = zr*fr - zi*fi; zi = zr*fi + zi*fr; zr = tr; }
        ar3 += w * zr; ai3 += w * zi; { float tr = zr*fr - zi*fi; zi = zr*fi + zi*fr; zr = tr; }
        ar4 += w * zr; ai4 += w * zi; { float tr = zr*fr - zi*fi; zi = zr*fi + zi*fr; zr = tr; }
        ar5 += w * zr; ai5 += w * zi; { float tr = zr*fr - zi*fi; zi = zr*fi + zi*fr; zr = tr; }
        ar6 += w * zr; ai6 += w * zi; { float tr = zr*fr - zi*fi; zi = zr*fi + zi*fr; zr = tr; }
        ar7 += w * zr; ai7 += w * zi;
    }

    const int wave = tid >> 6, lane = tid & 63;
    float acc[16] = {ar0,ai0,ar1,ai1,ar2,ai2,ar3,ai3,ar4,ai4,ar5,ai5,ar6,ai6,ar7,ai7};
#pragma unroll 16
    for (int v = 0; v < 16; ++v) {
        float x = acc[v];
        for (int off = 32; off > 0; off >>= 1) x += __shfl_down(x, off);
        if (lane == 0) lred[wave][v] = x;
    }
    __syncthreads();
    if (tid < 16) {
        float x = lred[0][tid] + lred[1][tid] + lred[2][tid] + lred[3][tid];
        int jj = tid >> 1, c = tid & 1;
        int n = n0 + jj;
        float ap = expf(-(DT_F / T2_F) * (float)n);
        x *= ap;
        fidfF[2 * n + c] = x;
        if (c == 0) out[n] = x;
    }
}

// split-K shifted-spectrum partials: 8 chunks x 32 k-groups
__global__ __launch_bounds__(256) void k_dft(const float2* __restrict__ fidf,
                                             float* __restrict__ part) {
    __shared__ float2 fs[512];
    const int tid = threadIdx.x;
    const int ch  = blockIdx.x >> 5;
    const int kb  = blockIdx.x & 31;
    const int n0  = ch * 512;
    fs[tid]       = fidf[n0 + tid];
    fs[tid + 256] = fidf[n0 + tid + 256];
    __syncthreads();
    const int k = kb * 256 + tid;
    const int K = (k + 4096) & 8191;
    const float C = TWO_PI / 8192.0f;
    int idx = (n0 * K) & 8191;
    float ar = 0.f;
    for (int i = 0; i < 512; ++i) {
        float2 s = fs[i];
        float sn, cs;
        __sincosf(C * (float)idx, &sn, &cs);
        ar += s.x * cs + s.y * sn;
        idx = (idx + K) & 8191;
    }
    part[ch * 8192 + k] = ar;
}

// reduce partials + write axes
__global__ void k_dredax(const float* __restrict__ part, float* __restrict__ out) {
    int i = blockIdx.x * 256 + threadIdx.x;   // 0..8191
    float s = 0.f;
#pragma unroll
    for (int ch = 0; ch < 8; ++ch) s += part[ch * 8192 + i];
    out[8192 + i] = s;
    out[16384 + i] = -0.5f * SW_F + (float)i * (SW_F / (float)(2 * N_SAMP - 1));
    if (i < N_SAMP)
        out[4096 + i] = (float)i * ((N_SAMP / SW_F) / (float)(N_SAMP - 1));
}

extern "C" void kernel_launch(void* const* d_in, const int* in_sizes, int n_in,
                              void* d_out, int out_size, void* d_ws, size_t ws_size,
                              hipStream_t stream) {
    const float* h = (const float*)d_in[0];
    float* out = (float*)d_out;
    float* ws  = (float*)d_ws;

    float*  Vt   = ws;
    float*  lam  = ws + 16384;
    float*  U    = ws + 16512;
    float*  M    = ws + 32896;
    float*  W    = ws + 49280;
    float*  fidfF= ws + 65664;
    float2* fidf = (float2*)(ws + 65664);
    float*  part = ws + 73856;

    k_eig<<<8, EIG_T, 0, stream>>>(h, Vt, lam);
    k_opv<<<64, 256, 0, stream>>>(Vt, U);
    k_m<<<128, 128, 0, stream>>>(Vt, U, M);
    k_w<<<64, 256, 0, stream>>>(M, W);
    k_fid<<<512, 256, 0, stream>>>(W, lam, fidfF, out);
    k_dft<<<256, 256, 0, stream>>>(fidf, part);
    k_dredax<<<32, 256, 0, stream>>>(part, out);
}

// Round 16
// 142.249 us; speedup vs baseline: 2.3167x; 1.2658x over previous
//
#include <hip/hip_runtime.h>
#include <math.h>

#define N_SAMP 4096
#define NS     7
#define DT_F   1e-5f
#define B0_F   80.0f
#define T2_F   1.0f
#define SW_F   1000.0f
#define TWO_PI 6.2831853071795864769f
#define NSWEEP_S 2
#define EIG_T  576   // 9 waves; jj = wave + rep*9 covers 18 pairs

// ws layout (floats): Vt 0..16384 | lam 16384..16512 | U 16512..32896 |
//                     W 49280..65664 | fidf(float2) 65664..73856 | part 73856..139392
// out (f32, 24576): ReFID [0,4096) | time [4096,8192) |
//                   Re shifted spec [8192,16384) | freq [16384,24576)

__global__ __launch_bounds__(EIG_T) void k_eig(const float* __restrict__ h,
                                               float* __restrict__ Vt_full,
                                               float* __restrict__ lam_out) {
    const int nsz_[8]   = {1, 7, 21, 35, 35, 21, 7, 1};
    const int nbase_[8] = {0, 1, 8, 29, 64, 99, 120, 127};
    const int s    = blockIdx.x;
    const int ns   = nsz_[s];
    const int base = nbase_[s];
    const int tid  = threadIdx.x;
    const int wave = tid >> 6;
    const int lane = tid & 63;

    __shared__ float As[36 * 37];
    __shared__ float Vs[36 * 37];
    __shared__ int   st[36];
    __shared__ float hs[49];
    __shared__ int   ppt[35 * 18];    // tournament table: (p<<8)|q per (round, pair)

    const int m      = ns + 1;        // sector sizes odd -> m even
    const int nr     = m - 1;
    const int npairs = m / 2;

    if (tid < 49) hs[tid] = h[tid];
    if (tid == 0) {
        int cnt = 0;
        for (int r = 0; r < 128; ++r) if (__popc(r) == s) st[cnt++] = r;
    }
    if (ns > 1) {
        for (int e = tid; e < nr * npairs; e += EIG_T) {
            int t = e / npairs, j = e - t * npairs;
            int p, q;
            if (j == 0) { p = t; q = m - 1; }
            else {
                int a1 = (t + j) % nr;
                int b1 = (t + nr - j) % nr;
                p = a1 < b1 ? a1 : b1;
                q = a1 < b1 ? b1 : a1;
            }
            ppt[t * npairs + j] = (p << 8) | q;
        }
    }
    for (int t = tid; t < 36 * 37; t += EIG_T) { As[t] = 0.f; Vs[t] = 0.f; }
    __syncthreads();

    // Build sector Hamiltonian from h
    for (int t = tid; t < ns * ns; t += EIG_T) {
        int i = t / ns, j = t % ns;
        int r = st[i], c = st[j];
        float val = 0.f;
        if (r == c) {
            float acc = 0.f;
            for (int a = 0; a < 7; ++a) {
                float za = ((r >> (6 - a)) & 1) ? -0.5f : 0.5f;
                acc += B0_F * hs[a * 7 + a] * za;
                for (int b = a + 1; b < 7; ++b) {
                    float zb = ((r >> (6 - b)) & 1) ? -0.5f : 0.5f;
                    acc += hs[a * 7 + b] * za * zb;
                }
            }
            val = TWO_PI * acc;
        } else {
            int x = r ^ c;
            if (__popc(x) == 2) {
                int u = 31 - __clz(x);
                int v = __ffs(x) - 1;
                if (((r >> u) & 1) != ((r >> v) & 1))
                    val = TWO_PI * 0.5f * hs[(6 - u) * 7 + (6 - v)];
            }
        }
        As[i * 37 + j] = val;
    }
    for (int i = tid; i < ns; i += EIG_T) Vs[i * 37 + i] = 1.f;
    __syncthreads();

    if (ns > 1) {
        for (int sweep = 0; sweep < NSWEEP_S; ++sweep) {
            for (int t = 0; t < nr; ++t) {
                const int* prow = &ppt[t * npairs];
                float c0 = 1.f, s0 = 0.f, c1 = 1.f, s1 = 0.f;
                int   pq0 = -1, pq1 = -1;

                // ---- phase R: A-rows + V-rows; (c,s) computed in-wave, kept in regs
#pragma unroll 2
                for (int rep = 0; rep < 2; ++rep) {
                    int jj = wave + rep * 9;
                    if (jj < npairs) {
                        int pq = prow[jj];
                        int p = pq >> 8, q = pq & 255;
                        if (q < ns) {
                            float app = As[p * 37 + p];
                            float aqq = As[q * 37 + q];
                            float apq = As[p * 37 + q];
                            float c = 1.f, sn = 0.f;
                            if (fabsf(apq) >= 1e-30f) {
                                float tau = (aqq - app) / (2.f * apq);
                                float tt  = copysignf(1.f / (fabsf(tau) + sqrtf(1.f + tau * tau)), tau);
                                c  = rsqrtf(1.f + tt * tt);
                                sn = tt * c;
                            }
                            if (rep == 0) { c0 = c; s0 = sn; pq0 = pq; }
                            else          { c1 = c; s1 = sn; pq1 = pq; }
                            if (lane < ns) {
                                float ap = As[p * 37 + lane], aq = As[q * 37 + lane];
                                As[p * 37 + lane] = c * ap - sn * aq;
                                As[q * 37 + lane] = sn * ap + c * aq;
                                float vp = Vs[p * 37 + lane], vq = Vs[q * 37 + lane];
                                Vs[p * 37 + lane] = c * vp - sn * vq;
                                Vs[q * 37 + lane] = sn * vp + c * vq;
                            }
                        }
                    }
                }
                __syncthreads();
                // ---- phase C: A-cols (registered (c,s))
                if (pq0 >= 0) {
                    int p = pq0 >> 8, q = pq0 & 255;
                    if (q < ns && lane < ns) {
                        float ap = As[lane * 37 + p], aq = As[lane * 37 + q];
                        As[lane * 37 + p] = c0 * ap - s0 * aq;
                        As[lane * 37 + q] = s0 * ap + c0 * aq;
                    }
                }
                if (pq1 >= 0) {
                    int p = pq1 >> 8, q = pq1 & 255;
                    if (q < ns && lane < ns) {
                        float ap = As[lane * 37 + p], aq = As[lane * 37 + q];
                        As[lane * 37 + p] = c1 * ap - s1 * aq;
                        As[lane * 37 + q] = s1 * ap + c1 * aq;
                    }
                }
                __syncthreads();
            }
        }
    }

    for (int i = tid; i < ns; i += EIG_T) lam_out[base + i] = As[i * 37 + i];
    for (int t = tid; t < ns * 128; t += EIG_T)
        Vt_full[(base + t / 128) * 128 + (t & 127)] = 0.f;
    __syncthreads();
    for (int t = tid; t < ns * ns; t += EIG_T) {
        int i = t / ns, j = t % ns;
        Vt_full[(base + i) * 128 + st[j]] = Vs[i * 37 + j];
    }
}

__global__ void k_opv(const float* __restrict__ Vt, float* __restrict__ U) {
    int idx = blockIdx.x * 256 + threadIdx.x;
    int b = idx >> 7, r = idx & 127;
    float acc = 0.f;
#pragma unroll
    for (int p = 0; p < 7; ++p)
        if (!((r >> p) & 1)) acc += Vt[b * 128 + r + (1 << p)];
    U[b * 128 + r] = acc;
}

// M[a][b] = Vt[a]·U[b]; sector structure => M[a][b]*M[b][a] == 0, so
// W = M ∘ (M+M^T)/2 = 0.5*M∘M  (no transpose needed)
__global__ void k_mw(const float* __restrict__ Vt, const float* __restrict__ U,
                     float* __restrict__ W) {
    __shared__ float va[128];
    int a = blockIdx.x, b = threadIdx.x;
    va[b] = Vt[a * 128 + b];
    __syncthreads();
    float acc = 0.f;
    for (int r = 0; r < 128; ++r) acc += va[r] * U[b * 128 + r];
    W[a * 128 + b] = 0.5f * acc * acc;
}

// 8 samples per block via phasor recurrence
__global__ __launch_bounds__(256) void k_fid(const float* __restrict__ W,
                                             const float* __restrict__ lam,
                                             float* __restrict__ fidfF,
                                             float* __restrict__ out) {
    __shared__ float2 cb0[128], dd[128];
    __shared__ float  lred[4][16];
    const int n0  = blockIdx.x * 8;
    const int tid = threadIdx.x;
    const float t0 = (float)n0 * DT_F;
    if (tid < 128) {
        float sn, cs;
        sincosf(lam[tid] * t0, &sn, &cs);
        cb0[tid] = make_float2(cs, -sn);
        sincosf(lam[tid] * DT_F, &sn, &cs);
        dd[tid] = make_float2(cs, -sn);
    }
    __syncthreads();

    float ar0=0,ar1=0,ar2=0,ar3=0,ar4=0,ar5=0,ar6=0,ar7=0;
    float ai0=0,ai1=0,ai2=0,ai3=0,ai4=0,ai5=0,ai6=0,ai7=0;
    for (int i = 0; i < 64; ++i) {
        int m = i * 256 + tid;
        int a = m >> 7, b = m & 127;
        float w = W[m];
        float2 ca = cb0[a], cbv = cb0[b];
        float2 da = dd[a],  db  = dd[b];
        float zr = ca.x * cbv.x + ca.y * cbv.y;
        float zi = ca.x * cbv.y - ca.y * cbv.x;
        float fr = da.x * db.x + da.y * db.y;
        float fi = da.x * db.y - da.y * db.x;
        ar0 += w * zr; ai0 += w * zi; { float tr = zr*fr - zi*fi; zi = zr*fi + zi*fr; zr = tr; }
        ar1 += w * zr; ai1 += w * zi; { float tr = zr*fr - zi*fi; zi = zr*fi + zi*fr; zr = tr; }
        ar2 += w * zr; ai2 += w * zi; { float tr = zr*fr - zi*fi; zi = zr*fi + zi*fr; zr = tr; }
        ar3 += w * zr; ai3 += w * zi; { float tr = zr*fr - zi*fi; zi = zr*fi + zi*fr; zr = tr; }
        ar4 += w * zr; ai4 += w * zi; { float tr = zr*fr - zi*fi; zi = zr*fi + zi*fr; zr = tr; }
        ar5 += w * zr; ai5 += w * zi; { float tr = zr*fr - zi*fi; zi = zr*fi + zi*fr; zr = tr; }
        ar6 += w * zr; ai6 += w * zi; { float tr = zr*fr - zi*fi; zi = zr*fi + zi*fr; zr = tr; }
        ar7 += w * zr; ai7 += w * zi;
    }

    const int wave = tid >> 6, lane = tid & 63;
    float acc[16] = {ar0,ai0,ar1,ai1,ar2,ai2,ar3,ai3,ar4,ai4,ar5,ai5,ar6,ai6,ar7,ai7};
#pragma unroll 16
    for (int v = 0; v < 16; ++v) {
        float x = acc[v];
        for (int off = 32; off > 0; off >>= 1) x += __shfl_down(x, off);
        if (lane == 0) lred[wave][v] = x;
    }
    __syncthreads();
    if (tid < 16) {
        float x = lred[0][tid] + lred[1][tid] + lred[2][tid] + lred[3][tid];
        int jj = tid >> 1, c = tid & 1;
        int n = n0 + jj;
        float ap = expf(-(DT_F / T2_F) * (float)n);
        x *= ap;
        fidfF[2 * n + c] = x;
        if (c == 0) out[n] = x;
    }
}

// split-K shifted-spectrum partials: 8 chunks x 32 k-groups
__global__ __launch_bounds__(256) void k_dft(const float2* __restrict__ fidf,
                                             float* __restrict__ part) {
    __shared__ float2 fs[512];
    const int tid = threadIdx.x;
    const int ch  = blockIdx.x >> 5;
    const int kb  = blockIdx.x & 31;
    const int n0  = ch * 512;
    fs[tid]       = fidf[n0 + tid];
    fs[tid + 256] = fidf[n0 + tid + 256];
    __syncthreads();
    const int k = kb * 256 + tid;
    const int K = (k + 4096) & 8191;
    const float C = TWO_PI / 8192.0f;
    int idx = (n0 * K) & 8191;
    float ar = 0.f;
    for (int i = 0; i < 512; ++i) {
        float2 s = fs[i];
        float sn, cs;
        __sincosf(C * (float)idx, &sn, &cs);
        ar += s.x * cs + s.y * sn;
        idx = (idx + K) & 8191;
    }
    part[ch * 8192 + k] = ar;
}

// reduce partials + write axes
__global__ void k_dredax(const float* __restrict__ part, float* __restrict__ out) {
    int i = blockIdx.x * 256 + threadIdx.x;   // 0..8191
    float s = 0.f;
#pragma unroll
    for (int ch = 0; ch < 8; ++ch) s += part[ch * 8192 + i];
    out[8192 + i] = s;
    out[16384 + i] = -0.5f * SW_F + (float)i * (SW_F / (float)(2 * N_SAMP - 1));
    if (i < N_SAMP)
        out[4096 + i] = (float)i * ((N_SAMP / SW_F) / (float)(N_SAMP - 1));
}

extern "C" void kernel_launch(void* const* d_in, const int* in_sizes, int n_in,
                              void* d_out, int out_size, void* d_ws, size_t ws_size,
                              hipStream_t stream) {
    const float* h = (const float*)d_in[0];
    float* out = (float*)d_out;
    float* ws  = (float*)d_ws;

    float*  Vt   = ws;
    float*  lam  = ws + 16384;
    float*  U    = ws + 16512;
    float*  W    = ws + 49280;
    float*  fidfF= ws + 65664;
    float2* fidf = (float2*)(ws + 65664);
    float*  part = ws + 73856;

    k_eig<<<8, EIG_T, 0, stream>>>(h, Vt, lam);
    k_opv<<<64, 256, 0, stream>>>(Vt, U);
    k_mw<<<128, 128, 0, stream>>>(Vt, U, W);
    k_fid<<<512, 256, 0, stream>>>(W, lam, fidfF, out);
    k_dft<<<256, 256, 0, stream>>>(fidf, part);
    k_dredax<<<32, 256, 0, stream>>>(part, out);
}

// Round 17
// 112.124 us; speedup vs baseline: 2.9391x; 1.2687x over previous
//
#include <hip/hip_runtime.h>
#include <math.h>

#define N_SAMP 4096
#define NS     7
#define DT_F   1e-5f
#define B0_F   80.0f
#define T2_F   1.0f
#define SW_F   1000.0f
#define TWO_PI 6.2831853071795864769f
#define NSWEEP_S 2
#define EIG_T  1024   // 16 waves: rep0 -> pairs 0..15, rep1 -> pairs 16..17 (waves 0,1)

// ws layout (floats): Vt 0..16384 | lam 16384..16512 | U 16512..32896 |
//                     wc 49280..52352 | ab(int) 52352..55424 |
//                     fidf(float2) 65664..73856 | part 73856..139392
// out (f32, 24576): ReFID [0,4096) | time [4096,8192) |
//                   Re shifted spec [8192,16384) | freq [16384,24576)

__global__ __launch_bounds__(EIG_T) void k_eig(const float* __restrict__ h,
                                               float* __restrict__ Vt_full,
                                               float* __restrict__ U,
                                               float* __restrict__ lam_out) {
    const int nsz_[8]   = {1, 7, 21, 35, 35, 21, 7, 1};
    const int nbase_[8] = {0, 1, 8, 29, 64, 99, 120, 127};
    const int s    = blockIdx.x;
    const int ns   = nsz_[s];
    const int base = nbase_[s];
    const int tid  = threadIdx.x;
    const int wave = tid >> 6;
    const int lane = tid & 63;

    __shared__ float As[36 * 37];
    __shared__ float Vs[36 * 37];
    __shared__ int   st[36];
    __shared__ int   inv[128];
    __shared__ float hs[49];
    __shared__ int   ppt[35 * 18];    // tournament table: (p<<8)|q per (round, pair)

    const int m      = ns + 1;        // sector sizes odd -> m even
    const int nr     = m - 1;
    const int npairs = m / 2;

    if (tid < 49) hs[tid] = h[tid];
    if (tid < 128) inv[tid] = 0;
    if (tid == 0) {
        int cnt = 0;
        for (int r = 0; r < 128; ++r) if (__popc(r) == s) st[cnt++] = r;
    }
    if (ns > 1) {
        for (int e = tid; e < nr * npairs; e += EIG_T) {
            int t = e / npairs, j = e - t * npairs;
            int p, q;
            if (j == 0) { p = t; q = m - 1; }
            else {
                int a1 = (t + j) % nr;
                int b1 = (t + nr - j) % nr;
                p = a1 < b1 ? a1 : b1;
                q = a1 < b1 ? b1 : a1;
            }
            ppt[t * npairs + j] = (p << 8) | q;
        }
    }
    for (int t = tid; t < 36 * 37; t += EIG_T) { As[t] = 0.f; Vs[t] = 0.f; }
    __syncthreads();

    if (tid < 128 && __popc(tid) == s) {
        // find index: count states below tid in sector (serialized per thread, tiny)
        int cnt = 0;
        for (int r = 0; r < 128; ++r) { if (r == tid) break; if (__popc(r) == s) ++cnt; }
        inv[tid] = cnt;
    }

    // Build sector Hamiltonian from h
    for (int t = tid; t < ns * ns; t += EIG_T) {
        int i = t / ns, j = t % ns;
        int r = st[i], c = st[j];
        float val = 0.f;
        if (r == c) {
            float acc = 0.f;
            for (int a = 0; a < 7; ++a) {
                float za = ((r >> (6 - a)) & 1) ? -0.5f : 0.5f;
                acc += B0_F * hs[a * 7 + a] * za;
                for (int b = a + 1; b < 7; ++b) {
                    float zb = ((r >> (6 - b)) & 1) ? -0.5f : 0.5f;
                    acc += hs[a * 7 + b] * za * zb;
                }
            }
            val = TWO_PI * acc;
        } else {
            int x = r ^ c;
            if (__popc(x) == 2) {
                int u = 31 - __clz(x);
                int v = __ffs(x) - 1;
                if (((r >> u) & 1) != ((r >> v) & 1))
                    val = TWO_PI * 0.5f * hs[(6 - u) * 7 + (6 - v)];
            }
        }
        As[i * 37 + j] = val;
    }
    for (int i = tid; i < ns; i += EIG_T) Vs[i * 37 + i] = 1.f;
    __syncthreads();

    if (ns > 1) {
        for (int sweep = 0; sweep < NSWEEP_S; ++sweep) {
            for (int t = 0; t < nr; ++t) {
                const int* prow = &ppt[t * npairs];
                float c0 = 1.f, s0 = 0.f, c1 = 1.f, s1 = 0.f;
                int   pq0 = -1, pq1 = -1;

                // ---- phase R: A-rows + V-rows; (c,s) computed in-wave, kept in regs
#pragma unroll 2
                for (int rep = 0; rep < 2; ++rep) {
                    int jj = wave + rep * 16;
                    if (jj < npairs) {
                        int pq = prow[jj];
                        int p = pq >> 8, q = pq & 255;
                        if (q < ns) {
                            float app = As[p * 37 + p];
                            float aqq = As[q * 37 + q];
                            float apq = As[p * 37 + q];
                            float c = 1.f, sn = 0.f;
                            if (fabsf(apq) >= 1e-30f) {
                                float tau = (aqq - app) / (2.f * apq);
                                float tt  = copysignf(1.f / (fabsf(tau) + sqrtf(1.f + tau * tau)), tau);
                                c  = rsqrtf(1.f + tt * tt);
                                sn = tt * c;
                            }
                            if (rep == 0) { c0 = c; s0 = sn; pq0 = pq; }
                            else          { c1 = c; s1 = sn; pq1 = pq; }
                            if (lane < ns) {
                                float ap = As[p * 37 + lane], aq = As[q * 37 + lane];
                                As[p * 37 + lane] = c * ap - sn * aq;
                                As[q * 37 + lane] = sn * ap + c * aq;
                                float vp = Vs[p * 37 + lane], vq = Vs[q * 37 + lane];
                                Vs[p * 37 + lane] = c * vp - sn * vq;
                                Vs[q * 37 + lane] = sn * vp + c * vq;
                            }
                        }
                    }
                }
                __syncthreads();
                // ---- phase C: A-cols (registered (c,s))
                if (pq0 >= 0) {
                    int p = pq0 >> 8, q = pq0 & 255;
                    if (q < ns && lane < ns) {
                        float ap = As[lane * 37 + p], aq = As[lane * 37 + q];
                        As[lane * 37 + p] = c0 * ap - s0 * aq;
                        As[lane * 37 + q] = s0 * ap + c0 * aq;
                    }
                }
                if (pq1 >= 0) {
                    int p = pq1 >> 8, q = pq1 & 255;
                    if (q < ns && lane < ns) {
                        float ap = As[lane * 37 + p], aq = As[lane * 37 + q];
                        As[lane * 37 + p] = c1 * ap - s1 * aq;
                        As[lane * 37 + q] = s1 * ap + c1 * aq;
                    }
                }
                __syncthreads();
            }
        }
    }

    for (int i = tid; i < ns; i += EIG_T) lam_out[base + i] = As[i * 37 + i];
    // single-pass Vt writeback + fused U = (Op V)^T rows for this sector
    for (int t = tid; t < ns * 128; t += EIG_T) {
        int i = t >> 7, r = t & 127;
        Vt_full[(base + i) * 128 + r] = (__popc(r) == s) ? Vs[i * 37 + inv[r]] : 0.f;
        float uval = 0.f;
        if (__popc(r) == s - 1) {
#pragma unroll
            for (int p = 0; p < 7; ++p)
                if (!((r >> p) & 1)) uval += Vs[i * 37 + inv[r + (1 << p)]];
        }
        U[(base + i) * 128 + r] = uval;
    }
}

// Compact W: only sector-pair (s -> s+1) entries are nonzero; 3003 entries,
// padded to 3072. wc[e] = 0.5*(Vt[a]·U[b])^2, ab[e] = (a<<7)|b.
__global__ __launch_bounds__(128) void k_mwc(const float* __restrict__ Vt,
                                             const float* __restrict__ U,
                                             float* __restrict__ wc,
                                             int* __restrict__ ab) {
    const int n2_[7]   = {7, 21, 35, 35, 21, 7, 1};
    const int offs_[7] = {0, 7, 154, 889, 2114, 2849, 2996};
    const int nb1_[7]  = {0, 1, 8, 29, 64, 99, 120};
    const int nb2_[7]  = {1, 8, 29, 64, 99, 120, 127};
    int e = blockIdx.x * 128 + threadIdx.x;
    if (e >= 3072) return;
    if (e >= 3003) { wc[e] = 0.f; ab[e] = 0; return; }
    int s = 0;
#pragma unroll
    for (int t = 1; t < 7; ++t) if (e >= offs_[t]) s = t;
    int loc = e - offs_[s];
    int i = loc / n2_[s];
    int j = loc - i * n2_[s];
    int a = nb1_[s] + i, b = nb2_[s] + j;
    float acc = 0.f;
    for (int r = 0; r < 128; ++r) acc += Vt[a * 128 + r] * U[b * 128 + r];
    wc[e] = 0.5f * acc * acc;
    ab[e] = (a << 7) | b;
}

// 8 samples per block via phasor recurrence over the 3072 compact entries
__global__ __launch_bounds__(256) void k_fid(const float* __restrict__ wc,
                                             const int* __restrict__ ab,
                                             const float* __restrict__ lam,
                                             float* __restrict__ fidfF,
                                             float* __restrict__ out) {
    __shared__ float2 cb0[128], dd[128];
    __shared__ float  lred[4][16];
    const int n0  = blockIdx.x * 8;
    const int tid = threadIdx.x;
    const float t0 = (float)n0 * DT_F;
    if (tid < 128) {
        float sn, cs;
        sincosf(lam[tid] * t0, &sn, &cs);
        cb0[tid] = make_float2(cs, -sn);
        sincosf(lam[tid] * DT_F, &sn, &cs);
        dd[tid] = make_float2(cs, -sn);
    }
    __syncthreads();

    float ar0=0,ar1=0,ar2=0,ar3=0,ar4=0,ar5=0,ar6=0,ar7=0;
    float ai0=0,ai1=0,ai2=0,ai3=0,ai4=0,ai5=0,ai6=0,ai7=0;
#pragma unroll 4
    for (int i = 0; i < 12; ++i) {
        int e = i * 256 + tid;
        float w = wc[e];
        int pq = ab[e];
        int a = pq >> 7, b = pq & 127;
        float2 ca = cb0[a], cbv = cb0[b];
        float2 da = dd[a],  db  = dd[b];
        float zr = ca.x * cbv.x + ca.y * cbv.y;
        float zi = ca.x * cbv.y - ca.y * cbv.x;
        float fr = da.x * db.x + da.y * db.y;
        float fi = da.x * db.y - da.y * db.x;
        ar0 += w * zr; ai0 += w * zi; { float tr = zr*fr - zi*fi; zi = zr*fi + zi*fr; zr = tr; }
        ar1 += w * zr; ai1 += w * zi; { float tr = zr*fr - zi*fi; zi = zr*fi + zi*fr; zr = tr; }
        ar2 += w * zr; ai2 += w * zi; { float tr = zr*fr - zi*fi; zi = zr*fi + zi*fr; zr = tr; }
        ar3 += w * zr; ai3 += w * zi; { float tr = zr*fr - zi*fi; zi = zr*fi + zi*fr; zr = tr; }
        ar4 += w * zr; ai4 += w * zi; { float tr = zr*fr - zi*fi; zi = zr*fi + zi*fr; zr = tr; }
        ar5 += w * zr; ai5 += w * zi; { float tr = zr*fr - zi*fi; zi = zr*fi + zi*fr; zr = tr; }
        ar6 += w * zr; ai6 += w * zi; { float tr = zr*fr - zi*fi; zi = zr*fi + zi*fr; zr = tr; }
        ar7 += w * zr; ai7 += w * zi;
    }

    const int wave = tid >> 6, lane = tid & 63;
    float acc[16] = {ar0,ai0,ar1,ai1,ar2,ai2,ar3,ai3,ar4,ai4,ar5,ai5,ar6,ai6,ar7,ai7};
#pragma unroll 16
    for (int v = 0; v < 16; ++v) {
        float x = acc[v];
        for (int off = 32; off > 0; off >>= 1) x += __shfl_down(x, off);
        if (lane == 0) lred[wave][v] = x;
    }
    __syncthreads();
    if (tid < 16) {
        float x = lred[0][tid] + lred[1][tid] + lred[2][tid] + lred[3][tid];
        int jj = tid >> 1, c = tid & 1;
        int n = n0 + jj;
        float ap = expf(-(DT_F / T2_F) * (float)n);
        x *= ap;
        fidfF[2 * n + c] = x;
        if (c == 0) out[n] = x;
    }
}

// split-K shifted-spectrum partials: 8 chunks x 32 k-groups
__global__ __launch_bounds__(256) void k_dft(const float2* __restrict__ fidf,
                                             float* __restrict__ part) {
    __shared__ float2 fs[512];
    const int tid = threadIdx.x;
    const int ch  = blockIdx.x >> 5;
    const int kb  = blockIdx.x & 31;
    const int n0  = ch * 512;
    fs[tid]       = fidf[n0 + tid];
    fs[tid + 256] = fidf[n0 + tid + 256];
    __syncthreads();
    const int k = kb * 256 + tid;
    const int K = (k + 4096) & 8191;
    const float C = TWO_PI / 8192.0f;
    int idx = (n0 * K) & 8191;
    float ar = 0.f;
    for (int i = 0; i < 512; ++i) {
        float2 s = fs[i];
        float sn, cs;
        __sincosf(C * (float)idx, &sn, &cs);
        ar += s.x * cs + s.y * sn;
        idx = (idx + K) & 8191;
    }
    part[ch * 8192 + k] = ar;
}

// reduce partials + write axes
__global__ void k_dredax(const float* __restrict__ part, float* __restrict__ out) {
    int i = blockIdx.x * 256 + threadIdx.x;   // 0..8191
    float s = 0.f;
#pragma unroll
    for (int ch = 0; ch < 8; ++ch) s += part[ch * 8192 + i];
    out[8192 + i] = s;
    out[16384 + i] = -0.5f * SW_F + (float)i * (SW_F / (float)(2 * N_SAMP - 1));
    if (i < N_SAMP)
        out[4096 + i] = (float)i * ((N_SAMP / SW_F) / (float)(N_SAMP - 1));
}

extern "C" void kernel_launch(void* const* d_in, const int* in_sizes, int n_in,
                              void* d_out, int out_size, void* d_ws, size_t ws_size,
                              hipStream_t stream) {
    const float* h = (const float*)d_in[0];
    float* out = (float*)d_out;
    float* ws  = (float*)d_ws;

    float*  Vt   = ws;
    float*  lam  = ws + 16384;
    float*  U    = ws + 16512;
    float*  wc   = ws + 49280;
    int*    ab   = (int*)(ws + 52352);
    float*  fidfF= ws + 65664;
    float2* fidf = (float2*)(ws + 65664);
    float*  part = ws + 73856;

    k_eig<<<8, EIG_T, 0, stream>>>(h, Vt, U, lam);
    k_mwc<<<24, 128, 0, stream>>>(Vt, U, wc, ab);
    k_fid<<<512, 256, 0, stream>>>(wc, ab, lam, fidfF, out);
    k_dft<<<256, 256, 0, stream>>>(fidf, part);
    k_dredax<<<32, 256, 0, stream>>>(part, out);
}

// Round 18
// 80.136 us; speedup vs baseline: 4.1123x; 1.3992x over previous
//
#include <hip/hip_runtime.h>
#include <math.h>

#define N_SAMP 4096
#define NS     7
#define DT_F   1e-5f
#define B0_F   80.0f
#define T2_F   1.0f
#define SW_F   1000.0f
#define TWO_PI 6.2831853071795864769f
#define NSWEEP_S 1
#define EIG_T  1024   // 16 waves: rep0 -> pairs 0..15, rep1 -> pairs 16..17 (waves 0,1)

// ws layout (floats): Vt 0..16384 | lam 16384..16512 | U 16512..32896 |
//                     wc 49280..52352 | ab(int) 52352..55424 |
//                     fidf(float2) 65664..73856 | part 73856..139392
// out (f32, 24576): ReFID [0,4096) | time [4096,8192) |
//                   Re shifted spec [8192,16384) | freq [16384,24576)

__global__ __launch_bounds__(EIG_T) void k_eig(const float* __restrict__ h,
                                               float* __restrict__ Vt_full,
                                               float* __restrict__ U,
                                               float* __restrict__ lam_out) {
    const int nsz_[8]   = {1, 7, 21, 35, 35, 21, 7, 1};
    const int nbase_[8] = {0, 1, 8, 29, 64, 99, 120, 127};
    const int s    = blockIdx.x;
    const int ns   = nsz_[s];
    const int base = nbase_[s];
    const int tid  = threadIdx.x;
    const int wave = tid >> 6;
    const int lane = tid & 63;

    __shared__ float As[36 * 37];
    __shared__ float Vs[36 * 37];
    __shared__ int   st[36];
    __shared__ int   inv[128];
    __shared__ float hs[49];
    __shared__ int   ppt[35 * 18];    // tournament table: (p<<8)|q per (round, pair)

    const int m      = ns + 1;        // sector sizes odd -> m even
    const int nr     = m - 1;
    const int npairs = m / 2;

    if (tid < 49) hs[tid] = h[tid];
    if (tid < 128) inv[tid] = 0;
    if (tid == 0) {
        int cnt = 0;
        for (int r = 0; r < 128; ++r) if (__popc(r) == s) st[cnt++] = r;
    }
    if (ns > 1) {
        for (int e = tid; e < nr * npairs; e += EIG_T) {
            int t = e / npairs, j = e - t * npairs;
            int p, q;
            if (j == 0) { p = t; q = m - 1; }
            else {
                int a1 = (t + j) % nr;
                int b1 = (t + nr - j) % nr;
                p = a1 < b1 ? a1 : b1;
                q = a1 < b1 ? b1 : a1;
            }
            ppt[t * npairs + j] = (p << 8) | q;
        }
    }
    for (int t = tid; t < 36 * 37; t += EIG_T) { As[t] = 0.f; Vs[t] = 0.f; }
    __syncthreads();

    if (tid < 128 && __popc(tid) == s) {
        int cnt = 0;
        for (int r = 0; r < 128; ++r) { if (r == tid) break; if (__popc(r) == s) ++cnt; }
        inv[tid] = cnt;
    }

    // Build sector Hamiltonian from h
    for (int t = tid; t < ns * ns; t += EIG_T) {
        int i = t / ns, j = t % ns;
        int r = st[i], c = st[j];
        float val = 0.f;
        if (r == c) {
            float acc = 0.f;
            for (int a = 0; a < 7; ++a) {
                float za = ((r >> (6 - a)) & 1) ? -0.5f : 0.5f;
                acc += B0_F * hs[a * 7 + a] * za;
                for (int b = a + 1; b < 7; ++b) {
                    float zb = ((r >> (6 - b)) & 1) ? -0.5f : 0.5f;
                    acc += hs[a * 7 + b] * za * zb;
                }
            }
            val = TWO_PI * acc;
        } else {
            int x = r ^ c;
            if (__popc(x) == 2) {
                int u = 31 - __clz(x);
                int v = __ffs(x) - 1;
                if (((r >> u) & 1) != ((r >> v) & 1))
                    val = TWO_PI * 0.5f * hs[(6 - u) * 7 + (6 - v)];
            }
        }
        As[i * 37 + j] = val;
    }
    for (int i = tid; i < ns; i += EIG_T) Vs[i * 37 + i] = 1.f;
    __syncthreads();

    if (ns > 1) {
        for (int sweep = 0; sweep < NSWEEP_S; ++sweep) {
            for (int t = 0; t < nr; ++t) {
                const int* prow = &ppt[t * npairs];
                float c0 = 1.f, s0 = 0.f, c1 = 1.f, s1 = 0.f;
                int   pq0 = -1, pq1 = -1;

                // ---- phase R: A-rows + V-rows; (c,s) computed in-wave, kept in regs
#pragma unroll 2
                for (int rep = 0; rep < 2; ++rep) {
                    int jj = wave + rep * 16;
                    if (jj < npairs) {
                        int pq = prow[jj];
                        int p = pq >> 8, q = pq & 255;
                        if (q < ns) {
                            float app = As[p * 37 + p];
                            float aqq = As[q * 37 + q];
                            float apq = As[p * 37 + q];
                            float c = 1.f, sn = 0.f;
                            if (fabsf(apq) >= 1e-30f) {
                                float tau = (aqq - app) / (2.f * apq);
                                float tt  = copysignf(1.f / (fabsf(tau) + sqrtf(1.f + tau * tau)), tau);
                                c  = rsqrtf(1.f + tt * tt);
                                sn = tt * c;
                            }
                            if (rep == 0) { c0 = c; s0 = sn; pq0 = pq; }
                            else          { c1 = c; s1 = sn; pq1 = pq; }
                            if (lane < ns) {
                                float ap = As[p * 37 + lane], aq = As[q * 37 + lane];
                                As[p * 37 + lane] = c * ap - sn * aq;
                                As[q * 37 + lane] = sn * ap + c * aq;
                                float vp = Vs[p * 37 + lane], vq = Vs[q * 37 + lane];
                                Vs[p * 37 + lane] = c * vp - sn * vq;
                                Vs[q * 37 + lane] = sn * vp + c * vq;
                            }
                        }
                    }
                }
                __syncthreads();
                // ---- phase C: A-cols (registered (c,s))
                if (pq0 >= 0) {
                    int p = pq0 >> 8, q = pq0 & 255;
                    if (q < ns && lane < ns) {
                        float ap = As[lane * 37 + p], aq = As[lane * 37 + q];
                        As[lane * 37 + p] = c0 * ap - s0 * aq;
                        As[lane * 37 + q] = s0 * ap + c0 * aq;
                    }
                }
                if (pq1 >= 0) {
                    int p = pq1 >> 8, q = pq1 & 255;
                    if (q < ns && lane < ns) {
                        float ap = As[lane * 37 + p], aq = As[lane * 37 + q];
                        As[lane * 37 + p] = c1 * ap - s1 * aq;
                        As[lane * 37 + q] = s1 * ap + c1 * aq;
                    }
                }
                __syncthreads();
            }
        }
    }

    for (int i = tid; i < ns; i += EIG_T) lam_out[base + i] = As[i * 37 + i];
    // single-pass Vt writeback + fused U = (Op V)^T rows for this sector
    for (int t = tid; t < ns * 128; t += EIG_T) {
        int i = t >> 7, r = t & 127;
        Vt_full[(base + i) * 128 + r] = (__popc(r) == s) ? Vs[i * 37 + inv[r]] : 0.f;
        float uval = 0.f;
        if (__popc(r) == s - 1) {
#pragma unroll
            for (int p = 0; p < 7; ++p)
                if (!((r >> p) & 1)) uval += Vs[i * 37 + inv[r + (1 << p)]];
        }
        U[(base + i) * 128 + r] = uval;
    }
}

// Compact W: only sector-pair (s -> s+1) entries are nonzero; 3003 entries,
// padded to 3072. wc[e] = 0.5*(Vt[a]·U[b])^2, ab[e] = (a<<7)|b.
__global__ __launch_bounds__(128) void k_mwc(const float* __restrict__ Vt,
                                             const float* __restrict__ U,
                                             float* __restrict__ wc,
                                             int* __restrict__ ab) {
    const int n2_[7]   = {7, 21, 35, 35, 21, 7, 1};
    const int offs_[7] = {0, 7, 154, 889, 2114, 2849, 2996};
    const int nb1_[7]  = {0, 1, 8, 29, 64, 99, 120};
    const int nb2_[7]  = {1, 8, 29, 64, 99, 120, 127};
    int e = blockIdx.x * 128 + threadIdx.x;
    if (e >= 3072) return;
    if (e >= 3003) { wc[e] = 0.f; ab[e] = 0; return; }
    int s = 0;
#pragma unroll
    for (int t = 1; t < 7; ++t) if (e >= offs_[t]) s = t;
    int loc = e - offs_[s];
    int i = loc / n2_[s];
    int j = loc - i * n2_[s];
    int a = nb1_[s] + i, b = nb2_[s] + j;
    float acc = 0.f;
    for (int r = 0; r < 128; ++r) acc += Vt[a * 128 + r] * U[b * 128 + r];
    wc[e] = 0.5f * acc * acc;
    ab[e] = (a << 7) | b;
}

// 8 samples per block via phasor recurrence over the 3072 compact entries
__global__ __launch_bounds__(256) void k_fid(const float* __restrict__ wc,
                                             const int* __restrict__ ab,
                                             const float* __restrict__ lam,
                                             float* __restrict__ fidfF,
                                             float* __restrict__ out) {
    __shared__ float2 cb0[128], dd[128];
    __shared__ float  lred[4][16];
    const int n0  = blockIdx.x * 8;
    const int tid = threadIdx.x;
    const float t0 = (float)n0 * DT_F;
    if (tid < 128) {
        float sn, cs;
        sincosf(lam[tid] * t0, &sn, &cs);
        cb0[tid] = make_float2(cs, -sn);
        sincosf(lam[tid] * DT_F, &sn, &cs);
        dd[tid] = make_float2(cs, -sn);
    }
    __syncthreads();

    float ar0=0,ar1=0,ar2=0,ar3=0,ar4=0,ar5=0,ar6=0,ar7=0;
    float ai0=0,ai1=0,ai2=0,ai3=0,ai4=0,ai5=0,ai6=0,ai7=0;
#pragma unroll 4
    for (int i = 0; i < 12; ++i) {
        int e = i * 256 + tid;
        float w = wc[e];
        int pq = ab[e];
        int a = pq >> 7, b = pq & 127;
        float2 ca = cb0[a], cbv = cb0[b];
        float2 da = dd[a],  db  = dd[b];
        float zr = ca.x * cbv.x + ca.y * cbv.y;
        float zi = ca.x * cbv.y - ca.y * cbv.x;
        float fr = da.x * db.x + da.y * db.y;
        float fi = da.x * db.y - da.y * db.x;
        ar0 += w * zr; ai0 += w * zi; { float tr = zr*fr - zi*fi; zi = zr*fi + zi*fr; zr = tr; }
        ar1 += w * zr; ai1 += w * zi; { float tr = zr*fr - zi*fi; zi = zr*fi + zi*fr; zr = tr; }
        ar2 += w * zr; ai2 += w * zi; { float tr = zr*fr - zi*fi; zi = zr*fi + zi*fr; zr = tr; }
        ar3 += w * zr; ai3 += w * zi; { float tr = zr*fr - zi*fi; zi = zr*fi + zi*fr; zr = tr; }
        ar4 += w * zr; ai4 += w * zi; { float tr = zr*fr - zi*fi; zi = zr*fi + zi*fr; zr = tr; }
        ar5 += w * zr; ai5 += w * zi; { float tr = zr*fr - zi*fi; zi = zr*fi + zi*fr; zr = tr; }
        ar6 += w * zr; ai6 += w * zi; { float tr = zr*fr - zi*fi; zi = zr*fi + zi*fr; zr = tr; }
        ar7 += w * zr; ai7 += w * zi;
    }

    const int wave = tid >> 6, lane = tid & 63;
    float acc[16] = {ar0,ai0,ar1,ai1,ar2,ai2,ar3,ai3,ar4,ai4,ar5,ai5,ar6,ai6,ar7,ai7};
#pragma unroll 16
    for (int v = 0; v < 16; ++v) {
        float x = acc[v];
        for (int off = 32; off > 0; off >>= 1) x += __shfl_down(x, off);
        if (lane == 0) lred[wave][v] = x;
    }
    __syncthreads();
    if (tid < 16) {
        float x = lred[0][tid] + lred[1][tid] + lred[2][tid] + lred[3][tid];
        int jj = tid >> 1, c = tid & 1;
        int n = n0 + jj;
        float ap = expf(-(DT_F / T2_F) * (float)n);
        x *= ap;
        fidfF[2 * n + c] = x;
        if (c == 0) out[n] = x;
    }
}

// split-K shifted-spectrum partials: 8 chunks x 32 k-groups
__global__ __launch_bounds__(256) void k_dft(const float2* __restrict__ fidf,
                                             float* __restrict__ part) {
    __shared__ float2 fs[512];
    const int tid = threadIdx.x;
    const int ch  = blockIdx.x >> 5;
    const int kb  = blockIdx.x & 31;
    const int n0  = ch * 512;
    fs[tid]       = fidf[n0 + tid];
    fs[tid + 256] = fidf[n0 + tid + 256];
    __syncthreads();
    const int k = kb * 256 + tid;
    const int K = (k + 4096) & 8191;
    const float C = TWO_PI / 8192.0f;
    int idx = (n0 * K) & 8191;
    float ar = 0.f;
    for (int i = 0; i < 512; ++i) {
        float2 s = fs[i];
        float sn, cs;
        __sincosf(C * (float)idx, &sn, &cs);
        ar += s.x * cs + s.y * sn;
        idx = (idx + K) & 8191;
    }
    part[ch * 8192 + k] = ar;
}

// reduce partials + write axes
__global__ void k_dredax(const float* __restrict__ part, float* __restrict__ out) {
    int i = blockIdx.x * 256 + threadIdx.x;   // 0..8191
    float s = 0.f;
#pragma unroll
    for (int ch = 0; ch < 8; ++ch) s += part[ch * 8192 + i];
    out[8192 + i] = s;
    out[16384 + i] = -0.5f * SW_F + (float)i * (SW_F / (float)(2 * N_SAMP - 1));
    if (i < N_SAMP)
        out[4096 + i] = (float)i * ((N_SAMP / SW_F) / (float)(N_SAMP - 1));
}

extern "C" void kernel_launch(void* const* d_in, const int* in_sizes, int n_in,
                              void* d_out, int out_size, void* d_ws, size_t ws_size,
                              hipStream_t stream) {
    const float* h = (const float*)d_in[0];
    float* out = (float*)d_out;
    float* ws  = (float*)d_ws;

    float*  Vt   = ws;
    float*  lam  = ws + 16384;
    float*  U    = ws + 16512;
    float*  wc   = ws + 49280;
    int*    ab   = (int*)(ws + 52352);
    float*  fidfF= ws + 65664;
    float2* fidf = (float2*)(ws + 65664);
    float*  part = ws + 73856;

    k_eig<<<8, EIG_T, 0, stream>>>(h, Vt, U, lam);
    k_mwc<<<24, 128, 0, stream>>>(Vt, U, wc, ab);
    k_fid<<<512, 256, 0, stream>>>(wc, ab, lam, fidfF, out);
    k_dft<<<256, 256, 0, stream>>>(fidf, part);
    k_dredax<<<32, 256, 0, stream>>>(part, out);
}